// Round 1
// baseline (1702.140 us; speedup 1.0000x reference)
//
#include <hip/hip_runtime.h>
#include <hip/hip_bf16.h>
#include <cstdint>

#define DEV __device__ __forceinline__

constexpr int B_ = 2, C_ = 256, H_ = 48, W_ = 48, D_ = 48, E_ = 32;
constexpr int WD_  = W_ * D_;      // 2304
constexpr int HWD_ = H_ * WD_;     // 110592
constexpr int NVOX_ = B_ * HWD_;   // 221184
constexpr int NOUT_ = 320;         // 32 q + 32 k + 256 v columns in WT

DEV unsigned short f2bf_bits(float f) {
    union { float f; unsigned u; } x; x.f = f;
    unsigned r = x.u + 0x7FFF + ((x.u >> 16) & 1);   // round-to-nearest-even
    return (unsigned short)(r >> 16);
}
DEV float bf2f(unsigned short s) {
    union { unsigned u; float f; } x; x.u = ((unsigned)s) << 16; return x.f;
}

// ---------------------------------------------------------------------------
// Weight transpose: WT[c][n], n: 0..31 = Wq rows, 32..63 = Wk rows, 64..319 = Wv rows.
// c-major so proj's inner loop indexes weights uniformly -> scalar s_load path.
// ---------------------------------------------------------------------------
__global__ void wtrans_kernel(const float* __restrict__ Wq, const float* __restrict__ Wk,
                              const float* __restrict__ Wv, float* __restrict__ WT) {
    int n = blockIdx.x;    // 0..319
    int c = threadIdx.x;   // 0..255
    float v;
    if (n < 32)      v = Wq[n * C_ + c];
    else if (n < 64) v = Wk[(n - 32) * C_ + c];
    else             v = Wv[(n - 64) * C_ + c];
    WT[c * NOUT_ + n] = v;
}

// ---------------------------------------------------------------------------
// Projection: thread = voxel, blockIdx.y = 64-wide output chunk.
// chunk 0..3 -> v[64*chunk .. ), chunk 4 -> q (32) + k (32).
// qT/kT: (vox, e) fp32; v: (vox, c) bf16.
// ---------------------------------------------------------------------------
__global__ __launch_bounds__(256) void proj_kernel(
        const float* __restrict__ query, const float* __restrict__ WT,
        const float* __restrict__ bq, const float* __restrict__ bk,
        const float* __restrict__ bv,
        float* __restrict__ qT, float* __restrict__ kT,
        unsigned short* __restrict__ vO) {
    const int t = threadIdx.x;
    const int vox = blockIdx.x * 256 + t;
    const int chunk = blockIdx.y;                       // 0..4
    const int b = vox / HWD_;
    const int sp = vox - b * HWD_;
    const float* qp = query + (size_t)b * C_ * HWD_ + sp;
    const int nbase = (chunk < 4) ? (64 + chunk * 64) : 0;  // WT column base
    float acc[64];
#pragma unroll
    for (int n = 0; n < 64; n++) acc[n] = 0.f;
    for (int c = 0; c < C_; c++) {
        const float x = qp[(size_t)c * HWD_];
        const float* wrow = WT + c * NOUT_ + nbase;     // uniform -> s_load
#pragma unroll
        for (int n = 0; n < 64; n++) acc[n] = fmaf(x, wrow[n], acc[n]);
    }
    if (chunk == 4) {
        const size_t basq = (size_t)vox * E_;
#pragma unroll
        for (int e = 0; e < E_; e++) qT[basq + e] = acc[e] + bq[e];
#pragma unroll
        for (int e = 0; e < E_; e++) kT[basq + e] = acc[32 + e] + bk[e];
    } else {
        const int vb0 = chunk * 64;
        const size_t basv = (size_t)vox * C_ + vb0;
#pragma unroll
        for (int n = 0; n < 64; n++) vO[basv + n] = f2bf_bits(acc[n] + bv[vb0 + n]);
    }
}

// ---------------------------------------------------------------------------
// Axis decode shared by stats/agg:
// axis 0 (H): block (b, w=i1, d=i2), line sp(i) = i*WD + w*D + d
// axis 1 (W): block (b, h=i1, d=i2), line sp(i) = h*WD + i*D + d
// axis 2 (D): block (b, h=i1, w=i2), line sp(i) = h*WD + w*D + i
// ---------------------------------------------------------------------------
DEV void axis_decode(int axis, int i1, int i2, int& base, int& stride) {
    if (axis == 0)      { base = i1 * D_ + i2;        stride = WD_; }
    else if (axis == 1) { base = i1 * WD_ + i2;       stride = D_;  }
    else                { base = i1 * WD_ + i2 * D_;  stride = 1;   }
}

// ---------------------------------------------------------------------------
// Per-axis softmax stats: per voxel-on-line max & sumexp of the 48 scores
// (H axis skips the diagonal y==x).
// ---------------------------------------------------------------------------
__global__ __launch_bounds__(256) void stats_kernel(
        const float* __restrict__ qT, const float* __restrict__ kT,
        float* __restrict__ mOut, float* __restrict__ sOut, int axis) {
    const int b  = blockIdx.y;
    const int i1 = blockIdx.x / 48;
    const int i2 = blockIdx.x - i1 * 48;
    int base, stride;
    axis_decode(axis, i1, i2, base, stride);
    __shared__ __align__(16) float qs[48][36];
    __shared__ __align__(16) float ks[48][36];
    __shared__ float pm[4][48], ps[4][48];
    const int t = threadIdx.x;
    const size_t vbase = (size_t)b * HWD_ + base;
    for (int j = t; j < 1536; j += 256) {
        int i = j >> 5, e = j & 31;
        size_t g = (vbase + (size_t)i * stride) * E_ + e;
        qs[i][e] = qT[g];
        ks[i][e] = kT[g];
    }
    __syncthreads();
    const int w = t >> 6, l = t & 63;
    if (l < 48) {
        float4 qv[8];
        const float4* qr = (const float4*)&qs[l][0];
#pragma unroll
        for (int i = 0; i < 8; i++) qv[i] = qr[i];
        float m = -1e30f, ssum = 0.f;
        float sv[12];
#pragma unroll
        for (int j = 0; j < 12; j++) {
            int y = w * 12 + j;
            const float4* kr = (const float4*)&ks[y][0];
            float s = 0.f;
#pragma unroll
            for (int i = 0; i < 8; i++) {
                float4 kv = kr[i];
                s = fmaf(qv[i].x, kv.x, fmaf(qv[i].y, kv.y,
                    fmaf(qv[i].z, kv.z, fmaf(qv[i].w, kv.w, s))));
            }
            sv[j] = s;
            bool masked = (axis == 0) && (y == l);
            if (!masked) m = fmaxf(m, s);
        }
#pragma unroll
        for (int j = 0; j < 12; j++) {
            int y = w * 12 + j;
            bool masked = (axis == 0) && (y == l);
            if (!masked) ssum += __expf(sv[j] - m);
        }
        pm[w][l] = m; ps[w][l] = ssum;
    }
    __syncthreads();
    if (t < 48) {
        float m = fmaxf(fmaxf(pm[0][t], pm[1][t]), fmaxf(pm[2][t], pm[3][t]));
        float s = ps[0][t] * __expf(pm[0][t] - m) + ps[1][t] * __expf(pm[1][t] - m)
                + ps[2][t] * __expf(pm[2][t] - m) + ps[3][t] * __expf(pm[3][t] - m);
        size_t vi = vbase + (size_t)t * stride;
        mOut[vi] = m; sOut[vi] = s;
    }
}

// Combine the three axes' stats into one normalizer Z = m + log(sum).
__global__ void combine_kernel(const float* __restrict__ mH, const float* __restrict__ sH,
                               const float* __restrict__ mW, const float* __restrict__ sW,
                               const float* __restrict__ mD, const float* __restrict__ sD,
                               float* __restrict__ Z) {
    int i = blockIdx.x * 256 + threadIdx.x;
    float m = fmaxf(fmaxf(mH[i], mW[i]), mD[i]);
    float s = sH[i] * __expf(mH[i] - m) + sW[i] * __expf(mW[i] - m)
            + sD[i] * __expf(mD[i] - m);
    Z[i] = m + __logf(s);
}

// ---------------------------------------------------------------------------
// Per-axis aggregation. axis 0 writes acc (=), axis 1 adds (+=),
// axis 2 produces final out = query + gamma*(acc + outD).
// ---------------------------------------------------------------------------
__global__ __launch_bounds__(256) void agg_kernel(
        const float* __restrict__ qT, const float* __restrict__ kT,
        const unsigned short* __restrict__ vI, const float* __restrict__ Z,
        float* __restrict__ accg,
        const float* __restrict__ query, const float* __restrict__ gamma,
        float* __restrict__ outp, int axis) {
    const int b  = blockIdx.y;
    const int i1 = blockIdx.x / 48;
    const int i2 = blockIdx.x - i1 * 48;
    int base, stride;
    axis_decode(axis, i1, i2, base, stride);
    __shared__ __align__(16) float qs[48][36];
    __shared__ __align__(16) float ks[48][36];
    __shared__ __align__(16) float P[48][52];          // P[y][x]
    __shared__ __align__(16) unsigned short vls[48][256];
    __shared__ float Zs[48];
    const int t = threadIdx.x;
    const size_t vbase = (size_t)b * HWD_ + base;

    for (int j = t; j < 1536; j += 256) {
        int i = j >> 5, e = j & 31;
        size_t g = (vbase + (size_t)i * stride) * E_ + e;
        qs[i][e] = qT[g];
        ks[i][e] = kT[g];
    }
    if (t < 48) Zs[t] = Z[vbase + (size_t)t * stride];
    for (int j = t; j < 1536; j += 256) {              // 48 lines x 32 uint4
        int i = j >> 5, ch = j & 31;
        const uint4* gp = (const uint4*)(vI + (vbase + (size_t)i * stride) * C_ + ch * 8);
        *((uint4*)&vls[i][ch * 8]) = *gp;
    }
    __syncthreads();

    const int w = t >> 6, l = t & 63;
    if (l < 48) {
        float4 qv[8];
        const float4* qr = (const float4*)&qs[l][0];
#pragma unroll
        for (int i = 0; i < 8; i++) qv[i] = qr[i];
        const float zx = Zs[l];
#pragma unroll
        for (int j = 0; j < 12; j++) {
            int y = w * 12 + j;
            const float4* kr = (const float4*)&ks[y][0];
            float s = 0.f;
#pragma unroll
            for (int i = 0; i < 8; i++) {
                float4 kv = kr[i];
                s = fmaf(qv[i].x, kv.x, fmaf(qv[i].y, kv.y,
                    fmaf(qv[i].z, kv.z, fmaf(qv[i].w, kv.w, s))));
            }
            P[y][l] = ((axis == 0) && (y == l)) ? 0.f : __expf(s - zx);
        }
    }
    __syncthreads();

    // thread t = channel c; out[x] = sum_y P[y][x] * v[y][c]
    float vlr[48];
#pragma unroll
    for (int y = 0; y < 48; y++) vlr[y] = bf2f(vls[y][t]);
    float acc[48];
#pragma unroll
    for (int x = 0; x < 48; x++) acc[x] = 0.f;
    for (int y = 0; y < 48; y++) {
        const float vv = vlr[y];
#pragma unroll
        for (int i = 0; i < 12; i++) {
            float4 p = *((const float4*)&P[y][4 * i]);
            acc[4 * i + 0] = fmaf(p.x, vv, acc[4 * i + 0]);
            acc[4 * i + 1] = fmaf(p.y, vv, acc[4 * i + 1]);
            acc[4 * i + 2] = fmaf(p.z, vv, acc[4 * i + 2]);
            acc[4 * i + 3] = fmaf(p.w, vv, acc[4 * i + 3]);
        }
    }

    if (axis == 0) {
#pragma unroll
        for (int x = 0; x < 48; x++)
            accg[(vbase + (size_t)x * stride) * C_ + t] = acc[x];
    } else if (axis == 1) {
#pragma unroll
        for (int x = 0; x < 48; x++) {
            size_t idx = (vbase + (size_t)x * stride) * C_ + t;
            accg[idx] += acc[x];
        }
    } else {
        const float g = gamma[0];
        const size_t obase = ((size_t)b * C_ + t) * HWD_ + base;   // + x (stride 1)
#pragma unroll
        for (int x = 0; x < 48; x++) {
            size_t vi = vbase + x;
            outp[obase + x] = fmaf(g, accg[vi * C_ + t] + acc[x], query[obase + x]);
        }
    }
}

// ---------------------------------------------------------------------------
extern "C" void kernel_launch(void* const* d_in, const int* in_sizes, int n_in,
                              void* d_out, int out_size, void* d_ws, size_t ws_size,
                              hipStream_t stream) {
    const float* query = (const float*)d_in[0];
    const float* Wq    = (const float*)d_in[1];
    const float* bq    = (const float*)d_in[2];
    const float* Wk    = (const float*)d_in[3];
    const float* bk    = (const float*)d_in[4];
    const float* Wv    = (const float*)d_in[5];
    const float* bv    = (const float*)d_in[6];
    const float* gamma = (const float*)d_in[7];
    float* outp = (float*)d_out;

    char* ws = (char*)d_ws;
    size_t off = 0;
    float* qT = (float*)(ws + off);           off += (size_t)NVOX_ * E_ * 4;   // 28.3 MB
    float* kT = (float*)(ws + off);           off += (size_t)NVOX_ * E_ * 4;   // 28.3 MB
    unsigned short* vB = (unsigned short*)(ws + off); off += (size_t)NVOX_ * C_ * 2; // 113 MB
    float* WT = (float*)(ws + off);           off += (size_t)NOUT_ * C_ * 4;   // 0.33 MB
    float* mS[3]; float* sS[3];
    for (int a = 0; a < 3; a++) {
        mS[a] = (float*)(ws + off); off += (size_t)NVOX_ * 4;
        sS[a] = (float*)(ws + off); off += (size_t)NVOX_ * 4;
    }
    float* Z = (float*)(ws + off);            off += (size_t)NVOX_ * 4;
    float* accg = (float*)(ws + off);         off += (size_t)NVOX_ * C_ * 4;   // 226 MB

    hipLaunchKernelGGL(wtrans_kernel, dim3(320), dim3(256), 0, stream, Wq, Wk, Wv, WT);
    hipLaunchKernelGGL(proj_kernel, dim3(NVOX_ / 256, 5), dim3(256), 0, stream,
                       query, WT, bq, bk, bv, qT, kT, vB);
    for (int axis = 0; axis < 3; axis++)
        hipLaunchKernelGGL(stats_kernel, dim3(2304, 2), dim3(256), 0, stream,
                           qT, kT, mS[axis], sS[axis], axis);
    hipLaunchKernelGGL(combine_kernel, dim3(NVOX_ / 256), dim3(256), 0, stream,
                       mS[0], sS[0], mS[1], sS[1], mS[2], sS[2], Z);
    for (int axis = 0; axis < 3; axis++)
        hipLaunchKernelGGL(agg_kernel, dim3(2304, 2), dim3(256), 0, stream,
                           qT, kT, vB, Z, accg, query, gamma, outp, axis);
}

// Round 2
// 1343.574 us; speedup vs baseline: 1.2669x; 1.2669x over previous
//
#include <hip/hip_runtime.h>
#include <hip/hip_bf16.h>
#include <cstdint>

#define DEV __device__ __forceinline__

constexpr int B_ = 2, C_ = 256, H_ = 48, W_ = 48, D_ = 48, E_ = 32;
constexpr int WD_  = W_ * D_;      // 2304
constexpr int HWD_ = H_ * WD_;     // 110592
constexpr int NVOX_ = B_ * HWD_;   // 221184

typedef __bf16 v8bf __attribute__((ext_vector_type(8)));
typedef float  f32x4 __attribute__((ext_vector_type(4)));

DEV unsigned short f2bf_bits(float f) {
    union { float f; unsigned u; } x; x.f = f;
    unsigned r = x.u + 0x7FFF + ((x.u >> 16) & 1);   // round-to-nearest-even
    return (unsigned short)(r >> 16);
}
DEV float bf2f(unsigned short s) {
    union { unsigned u; float f; } x; x.u = ((unsigned)s) << 16; return x.f;
}

// ---------------------------------------------------------------------------
// Wcat[m][c] bf16: m 0..31 Wq rows, 32..63 Wk rows, 64..319 Wv rows.
// ---------------------------------------------------------------------------
__global__ void wcat_kernel(const float* __restrict__ Wq, const float* __restrict__ Wk,
                            const float* __restrict__ Wv, unsigned short* __restrict__ Wcat) {
    int n = blockIdx.x;    // 0..319
    int c = threadIdx.x;   // 0..255
    float v;
    if (n < 32)      v = Wq[n * C_ + c];
    else if (n < 64) v = Wk[(n - 32) * C_ + c];
    else             v = Wv[(n - 64) * C_ + c];
    Wcat[n * C_ + c] = f2bf_bits(v);
}

// ---------------------------------------------------------------------------
// queryT[b][sp][c] bf16  <-  query[b][c][sp] fp32 (64x64 LDS tile transpose)
// ---------------------------------------------------------------------------
__global__ __launch_bounds__(256) void transpose_kernel(
        const float* __restrict__ query, unsigned short* __restrict__ queryT) {
    __shared__ float tile[64][65];
    const int t = threadIdx.x;
    const int tx = t & 63, ty = t >> 6;
    const int b = blockIdx.z, cb = blockIdx.y;
    const size_t sp0 = (size_t)blockIdx.x * 64;
    const float* src = query + ((size_t)b * C_ + cb * 64) * HWD_ + sp0;
#pragma unroll
    for (int r = 0; r < 16; r++) {
        int c = ty + 4 * r;
        tile[c][tx] = src[(size_t)c * HWD_ + tx];
    }
    __syncthreads();
    unsigned short* dst = queryT + ((size_t)b * HWD_ + sp0) * C_ + cb * 64;
#pragma unroll
    for (int r = 0; r < 16; r++) {
        int sp = ty + 4 * r;
        dst[(size_t)sp * C_ + tx] = f2bf_bits(tile[tx][sp]);
    }
}

// ---------------------------------------------------------------------------
// Projection GEMM: D[m][n] = sum_k Wcat[m][k] * queryT[n][k], MFMA bf16.
// Block: Mtile=64 (blockIdx.y selects which 64 of 320), Ntile=256 voxels.
// 4 waves, wave-tile 64m x 64n. Epilogue adds bias, routes q/k fp32, v bf16.
// ---------------------------------------------------------------------------
__global__ __launch_bounds__(256) void projgemm_kernel(
        const unsigned short* __restrict__ queryT, const unsigned short* __restrict__ Wcat,
        const float* __restrict__ bq, const float* __restrict__ bk,
        const float* __restrict__ bv,
        float* __restrict__ qT, float* __restrict__ kT,
        unsigned short* __restrict__ vO) {
    __shared__ unsigned short As[64][72];    // [m][k] bf16, pad 144B rows
    __shared__ unsigned short Bs[256][72];   // [n][k] bf16
    const int t = threadIdx.x;
    const int gy = blockIdx.y;               // m-block: 0=q+k, 1..4 = v
    const int bb = blockIdx.z;
    const size_t sp0 = (size_t)blockIdx.x * 256;
    const unsigned short* Asrc = Wcat + gy * 64 * C_;
    const unsigned short* Bsrc = queryT + ((size_t)bb * HWD_ + sp0) * C_;
    const int wv = t >> 6;                   // wave id: n-offset 64*wv
    const int lane = t & 63;
    const int ln = lane & 15, quad = lane >> 4;

    f32x4 acc[4][4];
#pragma unroll
    for (int mt = 0; mt < 4; mt++)
#pragma unroll
        for (int nt = 0; nt < 4; nt++) acc[mt][nt] = (f32x4){0.f, 0.f, 0.f, 0.f};

    for (int k0 = 0; k0 < C_; k0 += 64) {
        // stage A: 64x64 bf16 = 512 uint4
#pragma unroll
        for (int s = 0; s < 2; s++) {
            int i = t + s * 256;
            int m = i >> 3, ko = (i & 7) * 8;
            *(uint4*)&As[m][ko] = *(const uint4*)&Asrc[m * C_ + k0 + ko];
        }
        // stage B: 256x64 bf16 = 2048 uint4
#pragma unroll
        for (int s = 0; s < 8; s++) {
            int i = t + s * 256;
            int n = i >> 3, ko = (i & 7) * 8;
            *(uint4*)&Bs[n][ko] = *(const uint4*)&Bsrc[(size_t)n * C_ + k0 + ko];
        }
        __syncthreads();
#pragma unroll
        for (int ks = 0; ks < 64; ks += 32) {
            const int koffs = ks + quad * 8;
            v8bf af[4], bf[4];
#pragma unroll
            for (int mt = 0; mt < 4; mt++)
                af[mt] = *(const v8bf*)&As[16 * mt + ln][koffs];
#pragma unroll
            for (int nt = 0; nt < 4; nt++)
                bf[nt] = *(const v8bf*)&Bs[wv * 64 + 16 * nt + ln][koffs];
#pragma unroll
            for (int mt = 0; mt < 4; mt++)
#pragma unroll
                for (int nt = 0; nt < 4; nt++)
                    acc[mt][nt] = __builtin_amdgcn_mfma_f32_16x16x32_bf16(
                        af[mt], bf[nt], acc[mt][nt], 0, 0, 0);
        }
        __syncthreads();
    }

    // Epilogue: D row m = 16*mt + quad*4 + r, col n = wv*64 + 16*nt + ln.
#pragma unroll
    for (int mt = 0; mt < 4; mt++) {
#pragma unroll
        for (int r = 0; r < 4; r++) {
            const int ml = 16 * mt + quad * 4 + r;
            float bias;
            if (gy == 0) bias = (ml < 32) ? bq[ml] : bk[ml - 32];
            else         bias = bv[(gy - 1) * 64 + ml];
#pragma unroll
            for (int nt = 0; nt < 4; nt++) {
                const int n = wv * 64 + 16 * nt + ln;
                const size_t vox = (size_t)bb * HWD_ + sp0 + n;
                const float val = acc[mt][nt][r] + bias;
                if (gy == 0) {
                    if (ml < 32) qT[vox * E_ + ml] = val;
                    else         kT[vox * E_ + ml - 32] = val;
                } else {
                    vO[vox * C_ + (gy - 1) * 64 + ml] = f2bf_bits(val);
                }
            }
        }
    }
}

// ---------------------------------------------------------------------------
// axis 0 (H): block (b, w=i1, d=i2), line sp(i) = i*WD + w*D + d
// axis 1 (W): block (b, h=i1, d=i2), line sp(i) = h*WD + i*D + d
// axis 2 (D): block (b, h=i1, w=i2), line sp(i) = h*WD + w*D + i
// ---------------------------------------------------------------------------
DEV void axis_decode(int axis, int i1, int i2, int& base, int& stride) {
    if (axis == 0)      { base = i1 * D_ + i2;        stride = WD_; }
    else if (axis == 1) { base = i1 * WD_ + i2;       stride = D_;  }
    else                { base = i1 * WD_ + i2 * D_;  stride = 1;   }
}

// ---------------------------------------------------------------------------
// Per-axis softmax stats (max & sumexp of the 48 scores; H masks diag).
// ---------------------------------------------------------------------------
__global__ __launch_bounds__(256) void stats_kernel(
        const float* __restrict__ qT, const float* __restrict__ kT,
        float* __restrict__ mOut, float* __restrict__ sOut, int axis) {
    const int b  = blockIdx.y;
    const int i1 = blockIdx.x / 48;
    const int i2 = blockIdx.x - i1 * 48;
    int base, stride;
    axis_decode(axis, i1, i2, base, stride);
    __shared__ __align__(16) float qs[48][36];
    __shared__ __align__(16) float ks[48][36];
    __shared__ float pm[4][48], ps[4][48];
    const int t = threadIdx.x;
    const size_t vbase = (size_t)b * HWD_ + base;
    for (int j = t; j < 1536; j += 256) {
        int i = j >> 5, e = j & 31;
        size_t g = (vbase + (size_t)i * stride) * E_ + e;
        qs[i][e] = qT[g];
        ks[i][e] = kT[g];
    }
    __syncthreads();
    const int w = t >> 6, l = t & 63;
    if (l < 48) {
        float4 qv[8];
        const float4* qr = (const float4*)&qs[l][0];
#pragma unroll
        for (int i = 0; i < 8; i++) qv[i] = qr[i];
        float m = -1e30f, ssum = 0.f;
        float sv[12];
#pragma unroll
        for (int j = 0; j < 12; j++) {
            int y = w * 12 + j;
            const float4* kr = (const float4*)&ks[y][0];
            float s = 0.f;
#pragma unroll
            for (int i = 0; i < 8; i++) {
                float4 kv = kr[i];
                s = fmaf(qv[i].x, kv.x, fmaf(qv[i].y, kv.y,
                    fmaf(qv[i].z, kv.z, fmaf(qv[i].w, kv.w, s))));
            }
            sv[j] = s;
            bool masked = (axis == 0) && (y == l);
            if (!masked) m = fmaxf(m, s);
        }
#pragma unroll
        for (int j = 0; j < 12; j++) {
            int y = w * 12 + j;
            bool masked = (axis == 0) && (y == l);
            if (!masked) ssum += __expf(sv[j] - m);
        }
        pm[w][l] = m; ps[w][l] = ssum;
    }
    __syncthreads();
    if (t < 48) {
        float m = fmaxf(fmaxf(pm[0][t], pm[1][t]), fmaxf(pm[2][t], pm[3][t]));
        float s = ps[0][t] * __expf(pm[0][t] - m) + ps[1][t] * __expf(pm[1][t] - m)
                + ps[2][t] * __expf(pm[2][t] - m) + ps[3][t] * __expf(pm[3][t] - m);
        size_t vi = vbase + (size_t)t * stride;
        mOut[vi] = m; sOut[vi] = s;
    }
}

__global__ void combine_kernel(const float* __restrict__ mH, const float* __restrict__ sH,
                               const float* __restrict__ mW, const float* __restrict__ sW,
                               const float* __restrict__ mD, const float* __restrict__ sD,
                               float* __restrict__ Z) {
    int i = blockIdx.x * 256 + threadIdx.x;
    float m = fmaxf(fmaxf(mH[i], mW[i]), mD[i]);
    float s = sH[i] * __expf(mH[i] - m) + sW[i] * __expf(mW[i] - m)
            + sD[i] * __expf(mD[i] - m);
    Z[i] = m + __logf(s);
}

// ---------------------------------------------------------------------------
// Per-axis aggregation. Consumer mapping: wave = x-group (12 x), lane = 4 ch.
// axis 0 writes acc (=), axis 1 adds (+=), axis 2: out = query + g*(acc+outD).
// ---------------------------------------------------------------------------
__global__ __launch_bounds__(256) void agg_kernel(
        const float* __restrict__ qT, const float* __restrict__ kT,
        const unsigned short* __restrict__ vI, const float* __restrict__ Z,
        float* __restrict__ accg,
        const float* __restrict__ query, const float* __restrict__ gamma,
        float* __restrict__ outp, int axis) {
    const int b  = blockIdx.y;
    const int i1 = blockIdx.x / 48;
    const int i2 = blockIdx.x - i1 * 48;
    int base, stride;
    axis_decode(axis, i1, i2, base, stride);
    __shared__ __align__(16) float qs[48][36];
    __shared__ __align__(16) float ks[48][36];
    __shared__ __align__(16) float P[48][52];          // P[y][x]
    __shared__ __align__(16) unsigned short vls[48][256];
    __shared__ float Zs[48];
    const int t = threadIdx.x;
    const size_t vbase = (size_t)b * HWD_ + base;

    for (int j = t; j < 1536; j += 256) {
        int i = j >> 5, e = j & 31;
        size_t g = (vbase + (size_t)i * stride) * E_ + e;
        qs[i][e] = qT[g];
        ks[i][e] = kT[g];
    }
    if (t < 48) Zs[t] = Z[vbase + (size_t)t * stride];
    for (int j = t; j < 1536; j += 256) {              // 48 lines x 32 uint4
        int i = j >> 5, ch = j & 31;
        const uint4* gp = (const uint4*)(vI + (vbase + (size_t)i * stride) * C_ + ch * 8);
        *((uint4*)&vls[i][ch * 8]) = *gp;
    }
    __syncthreads();

    {   // producer: lane l computes P[y][l] for 12 y's
        const int w = t >> 6, l = t & 63;
        if (l < 48) {
            float4 qv[8];
            const float4* qr = (const float4*)&qs[l][0];
#pragma unroll
            for (int i = 0; i < 8; i++) qv[i] = qr[i];
            const float zx = Zs[l];
#pragma unroll
            for (int j = 0; j < 12; j++) {
                int y = w * 12 + j;
                const float4* kr = (const float4*)&ks[y][0];
                float s = 0.f;
#pragma unroll
                for (int i = 0; i < 8; i++) {
                    float4 kv = kr[i];
                    s = fmaf(qv[i].x, kv.x, fmaf(qv[i].y, kv.y,
                        fmaf(qv[i].z, kv.z, fmaf(qv[i].w, kv.w, s))));
                }
                P[y][l] = ((axis == 0) && (y == l)) ? 0.f : __expf(s - zx);
            }
        }
    }
    __syncthreads();

    // consumer: wave wv owns x in [12wv, 12wv+12), lane l owns ch 4l..4l+3
    const int wv = t >> 6, l = t & 63;
    float accf[12][4];
#pragma unroll
    for (int i = 0; i < 12; i++)
#pragma unroll
        for (int j = 0; j < 4; j++) accf[i][j] = 0.f;

    for (int y = 0; y < 48; y++) {
        float4 p0 = *(const float4*)&P[y][12 * wv + 0];
        float4 p1 = *(const float4*)&P[y][12 * wv + 4];
        float4 p2 = *(const float4*)&P[y][12 * wv + 8];
        ushort4 vvv = *(const ushort4*)&vls[y][4 * l];
        float v0 = bf2f(vvv.x), v1 = bf2f(vvv.y), v2 = bf2f(vvv.z), v3 = bf2f(vvv.w);
        float pv[12] = {p0.x, p0.y, p0.z, p0.w, p1.x, p1.y, p1.z, p1.w,
                        p2.x, p2.y, p2.z, p2.w};
#pragma unroll
        for (int i = 0; i < 12; i++) {
            accf[i][0] = fmaf(pv[i], v0, accf[i][0]);
            accf[i][1] = fmaf(pv[i], v1, accf[i][1]);
            accf[i][2] = fmaf(pv[i], v2, accf[i][2]);
            accf[i][3] = fmaf(pv[i], v3, accf[i][3]);
        }
    }

    if (axis == 0) {
#pragma unroll
        for (int i = 0; i < 12; i++) {
            size_t idx = (vbase + (size_t)(12 * wv + i) * stride) * C_ + 4 * l;
            *(float4*)&accg[idx] = make_float4(accf[i][0], accf[i][1], accf[i][2], accf[i][3]);
        }
    } else if (axis == 1) {
#pragma unroll
        for (int i = 0; i < 12; i++) {
            size_t idx = (vbase + (size_t)(12 * wv + i) * stride) * C_ + 4 * l;
            float4 old = *(const float4*)&accg[idx];
            *(float4*)&accg[idx] = make_float4(accf[i][0] + old.x, accf[i][1] + old.y,
                                               accf[i][2] + old.z, accf[i][3] + old.w);
        }
    } else {
        const float g = gamma[0];
        float acc2[12][4];
#pragma unroll
        for (int i = 0; i < 12; i++) {
            float4 av = *(const float4*)&accg[(vbase + 12 * wv + i) * C_ + 4 * l];
            acc2[i][0] = accf[i][0] + av.x; acc2[i][1] = accf[i][1] + av.y;
            acc2[i][2] = accf[i][2] + av.z; acc2[i][3] = accf[i][3] + av.w;
        }
#pragma unroll
        for (int j = 0; j < 4; j++) {
            const int c = 4 * l + j;
            const size_t ob = ((size_t)b * C_ + c) * HWD_ + base + 12 * wv;
#pragma unroll
            for (int gq = 0; gq < 3; gq++) {
                float4 qv = *(const float4*)&query[ob + 4 * gq];
                float4 o;
                o.x = fmaf(g, acc2[4 * gq + 0][j], qv.x);
                o.y = fmaf(g, acc2[4 * gq + 1][j], qv.y);
                o.z = fmaf(g, acc2[4 * gq + 2][j], qv.z);
                o.w = fmaf(g, acc2[4 * gq + 3][j], qv.w);
                *(float4*)&outp[ob + 4 * gq] = o;
            }
        }
    }
}

// ---------------------------------------------------------------------------
extern "C" void kernel_launch(void* const* d_in, const int* in_sizes, int n_in,
                              void* d_out, int out_size, void* d_ws, size_t ws_size,
                              hipStream_t stream) {
    const float* query = (const float*)d_in[0];
    const float* Wq    = (const float*)d_in[1];
    const float* bq    = (const float*)d_in[2];
    const float* Wk    = (const float*)d_in[3];
    const float* bk    = (const float*)d_in[4];
    const float* Wv    = (const float*)d_in[5];
    const float* bv    = (const float*)d_in[6];
    const float* gamma = (const float*)d_in[7];
    float* outp = (float*)d_out;

    char* ws = (char*)d_ws;
    size_t off = 0;
    float* qT = (float*)(ws + off);           off += (size_t)NVOX_ * E_ * 4;   // 28.3 MB
    float* kT = (float*)(ws + off);           off += (size_t)NVOX_ * E_ * 4;   // 28.3 MB
    unsigned short* vB = (unsigned short*)(ws + off); off += (size_t)NVOX_ * C_ * 2; // 113 MB
    unsigned short* Wcat = (unsigned short*)(ws + off); off += (size_t)320 * C_ * 2;
    float* mS[3]; float* sS[3];
    for (int a = 0; a < 3; a++) {
        mS[a] = (float*)(ws + off); off += (size_t)NVOX_ * 4;
        sS[a] = (float*)(ws + off); off += (size_t)NVOX_ * 4;
    }
    float* Z = (float*)(ws + off);            off += (size_t)NVOX_ * 4;
    float* accg = (float*)(ws + off);         off += (size_t)NVOX_ * C_ * 4;   // 226 MB
    // queryT (113 MB bf16) aliases accg: dead before agg axis-0 writes accg.
    unsigned short* queryT = (unsigned short*)accg;

    hipLaunchKernelGGL(wcat_kernel, dim3(320), dim3(256), 0, stream, Wq, Wk, Wv, Wcat);
    hipLaunchKernelGGL(transpose_kernel, dim3(HWD_ / 64, 4, 2), dim3(256), 0, stream,
                       query, queryT);
    hipLaunchKernelGGL(projgemm_kernel, dim3(HWD_ / 256, 5, 2), dim3(256), 0, stream,
                       queryT, Wcat, bq, bk, bv, qT, kT, vB);
    for (int axis = 0; axis < 3; axis++)
        hipLaunchKernelGGL(stats_kernel, dim3(2304, 2), dim3(256), 0, stream,
                           qT, kT, mS[axis], sS[axis], axis);
    hipLaunchKernelGGL(combine_kernel, dim3(NVOX_ / 256), dim3(256), 0, stream,
                       mS[0], sS[0], mS[1], sS[1], mS[2], sS[2], Z);
    for (int axis = 0; axis < 3; axis++)
        hipLaunchKernelGGL(agg_kernel, dim3(2304, 2), dim3(256), 0, stream,
                           qT, kT, vB, Z, accg, query, gamma, outp, axis);
}